// Round 1
// baseline (3367.969 us; speedup 1.0000x reference)
//
#include <hip/hip_runtime.h>
#include <math.h>

// Problem constants
#define BATCH   256
#define T_STEPS 4096
#define IN_DIM  28
#define HID     128
#define GATES   512   // 4*HID
#define OUT_DIM 10

__device__ __forceinline__ float frcp_fast(float x) {
    return __builtin_amdgcn_rcpf(x);
}

__device__ __forceinline__ float sigm(float x) {
    // 1/(1+exp(-x)); exp(-x)->inf for very negative x gives 0, ->0 gives 1. Safe.
    return frcp_fast(1.0f + __expf(-x));
}

__device__ __forceinline__ float tanh_fast(float x) {
    // tanh(x) = sign(x) * (1 - e) / (1 + e), e = exp(-2|x|)  (no overflow)
    float ax = fabsf(x);
    float e  = __expf(-2.0f * ax);
    float r  = (1.0f - e) * frcp_fast(1.0f + e);
    return copysignf(r, x);
}

// ---------------------------------------------------------------------------
// Kernel 1: input projection for batch element 255 only.
// gx[t, g] = dot(x255[t, :], w_ih[g, :]) + b_ih[g] + b_hh[g]
// ---------------------------------------------------------------------------
__global__ __launch_bounds__(GATES) void k_inproj(const float* __restrict__ x255,
                                                  const float* __restrict__ w_ih,
                                                  const float* __restrict__ b_ih,
                                                  const float* __restrict__ b_hh,
                                                  float* __restrict__ gx) {
    const int t = blockIdx.x;
    const int g = threadIdx.x;
    __shared__ float xs[IN_DIM];
    if (g < IN_DIM) xs[g] = x255[t * IN_DIM + g];
    __syncthreads();
    float acc = b_ih[g] + b_hh[g];
    const float* __restrict__ wr = w_ih + g * IN_DIM;
#pragma unroll
    for (int k = 0; k < IN_DIM; ++k) acc += wr[k] * xs[k];
    gx[t * GATES + g] = acc;
}

// ---------------------------------------------------------------------------
// Kernel 2: the sequential LSTM scan — single workgroup, 512 threads.
// Thread g owns gate-row g; w_hh[g, :] lives in 32 float4 VGPRs.
// Per step: preact dot from LDS-broadcast h, per-thread activation,
// threads 0..127 do the c/h update. Two barriers per step.
// FUSED=true computes the input projection inline (fallback when d_ws is
// too small for the precomputed gx buffer).
// ---------------------------------------------------------------------------
template <bool FUSED>
__global__ __launch_bounds__(GATES) void k_scan(const float* __restrict__ gx,
                                                const float* __restrict__ w_hh,
                                                float* __restrict__ hs,
                                                const float* __restrict__ x255,
                                                const float* __restrict__ w_ih,
                                                const float* __restrict__ b_ih,
                                                const float* __restrict__ b_hh) {
    const int g    = threadIdx.x;   // 0..511
    const int quad = g >> 7;        // 0:i 1:f 2:g 3:o

    __shared__ float h_sh[HID];
    __shared__ float act_sh[GATES];
    __shared__ float xs[IN_DIM];

    // Recurrent weights: row g of w_hh, held in registers (32 float4 = 128 VGPR).
    float4 wv[HID / 4];
    const float4* __restrict__ wrow = reinterpret_cast<const float4*>(w_hh + g * HID);
#pragma unroll
    for (int k = 0; k < HID / 4; ++k) wv[k] = wrow[k];

    float wih[FUSED ? IN_DIM : 1];
    float bsum = 0.0f;
    if (FUSED) {
        bsum = b_ih[g] + b_hh[g];
#pragma unroll
        for (int k = 0; k < IN_DIM; ++k) wih[k] = w_ih[g * IN_DIM + k];
    }

    if (g < HID) h_sh[g] = 0.0f;
    float c = 0.0f;     // cell state for unit g (threads 0..127 only use it)
    __syncthreads();

    float gnext = 0.0f;
    if (!FUSED) gnext = gx[g];   // prefetch step 0

    for (int t = 0; t < T_STEPS; ++t) {
        float a0, a1 = 0.0f, a2 = 0.0f, a3 = 0.0f;
        if (FUSED) {
            __syncthreads();   // protect xs from previous step's readers
            if (g < IN_DIM) xs[g] = x255[t * IN_DIM + g];
            __syncthreads();
            float acc = bsum;
#pragma unroll
            for (int k = 0; k < IN_DIM; ++k) acc += wih[k] * xs[k];
            a0 = acc;
        } else {
            a0 = gnext;
            if (t + 1 < T_STEPS) gnext = gx[(t + 1) * GATES + g];  // prefetch next step
        }

        // preact = gx + dot(w_hh[g,:], h)  — h broadcast from LDS (b128, uniform addr)
        const float4* __restrict__ h4 = reinterpret_cast<const float4*>(h_sh);
#pragma unroll
        for (int k = 0; k < HID / 4; ++k) {
            float4 hv = h4[k];
            a0 += wv[k].x * hv.x;
            a1 += wv[k].y * hv.y;
            a2 += wv[k].z * hv.z;
            a3 += wv[k].w * hv.w;
        }
        float pre = (a0 + a1) + (a2 + a3);

        // per-thread activation (gate order i, f, g, o)
        float a = (quad == 2) ? tanh_fast(pre) : sigm(pre);
        act_sh[g] = a;
        __syncthreads();   // barrier 1: preacts ready; also protects h_sh read->write

        if (g < HID) {
            float iv = act_sh[g];
            float fv = act_sh[HID + g];
            float gv = act_sh[2 * HID + g];
            float ov = act_sh[3 * HID + g];
            c = fv * c + iv * gv;
            float h = ov * tanh_fast(c);
            h_sh[g] = h;
            hs[t * HID + g] = h;   // fire-and-forget global store (512 B/step)
        }
        __syncthreads();   // barrier 2: h ready for next step's dot; act_sh reusable
    }
}

// ---------------------------------------------------------------------------
// Kernel 3: final FC — out[t, o] = dot(hs[t, :], w_fc[o, :]) + b_fc[o]
// ---------------------------------------------------------------------------
__global__ __launch_bounds__(256) void k_fc(const float* __restrict__ hs,
                                            const float* __restrict__ w_fc,
                                            const float* __restrict__ b_fc,
                                            float* __restrict__ out) {
    const int idx = blockIdx.x * blockDim.x + threadIdx.x;
    if (idx >= T_STEPS * OUT_DIM) return;
    const int t = idx / OUT_DIM;
    const int o = idx - t * OUT_DIM;
    const float* __restrict__ hrow = hs + t * HID;
    const float* __restrict__ wrow = w_fc + o * HID;
    float acc = b_fc[o];
#pragma unroll 8
    for (int k = 0; k < HID; ++k) acc += hrow[k] * wrow[k];
    out[idx] = acc;
}

// ---------------------------------------------------------------------------
extern "C" void kernel_launch(void* const* d_in, const int* in_sizes, int n_in,
                              void* d_out, int out_size, void* d_ws, size_t ws_size,
                              hipStream_t stream) {
    const float* x    = (const float*)d_in[0];  // [B, T, I]
    const float* w_ih = (const float*)d_in[1];  // [4H, I]
    const float* w_hh = (const float*)d_in[2];  // [4H, H]
    const float* b_ih = (const float*)d_in[3];  // [4H]
    const float* b_hh = (const float*)d_in[4];  // [4H]
    const float* w_fc = (const float*)d_in[5];  // [OUT, H]
    const float* b_fc = (const float*)d_in[6];  // [OUT]
    float* out = (float*)d_out;                 // [T, OUT]

    // Only batch element B-1 is observable in the reference output.
    const float* x255 = x + (size_t)(BATCH - 1) * T_STEPS * IN_DIM;

    float* hs = (float*)d_ws;                                  // 4096*128 f32 = 2 MB
    float* gxbuf = hs + (size_t)T_STEPS * HID;                 // 4096*512 f32 = 8 MB
    const size_t need_full = (size_t)(T_STEPS * HID + T_STEPS * GATES) * sizeof(float);

    if (ws_size >= need_full) {
        k_inproj<<<T_STEPS, GATES, 0, stream>>>(x255, w_ih, b_ih, b_hh, gxbuf);
        k_scan<false><<<1, GATES, 0, stream>>>(gxbuf, w_hh, hs, x255, w_ih, b_ih, b_hh);
    } else {
        // Fallback: compute input projection inline (needs only the 2 MB hs buffer).
        k_scan<true><<<1, GATES, 0, stream>>>(nullptr, w_hh, hs, x255, w_ih, b_ih, b_hh);
    }

    const int n = T_STEPS * OUT_DIM;
    k_fc<<<(n + 255) / 256, 256, 0, stream>>>(hs, w_fc, b_fc, out);
}